// Round 5
// baseline (348.269 us; speedup 1.0000x reference)
//
#include <hip/hip_runtime.h>
#include <cstdint>
#include <cstddef>

typedef unsigned short u16;
typedef unsigned char u8;
typedef unsigned int u32;
typedef __bf16 bf16x8 __attribute__((ext_vector_type(8)));
typedef float floatx4 __attribute__((ext_vector_type(4)));
typedef float floatx16 __attribute__((ext_vector_type(16)));
typedef int i32x8 __attribute__((ext_vector_type(8)));

#define B_ 2
#define S_ 2048
#define D_ 1024
#define H_ 16
#define DFF_ 4096
#define BS_ 4096   // B_*S_

__device__ __forceinline__ u16 f2bf(float f) {
  u32 u = __builtin_bit_cast(u32, f);
  u += 0x7fffu + ((u >> 16) & 1u);
  return (u16)(u >> 16);
}
__device__ __forceinline__ float bf2f(u16 h) {
  u32 u = ((u32)h) << 16;
  return __builtin_bit_cast(float, u);
}

// packed f32x2 -> bf16x2 (RNE), single instruction
__device__ __forceinline__ u32 cvtpk_bf16(float lo, float hi) {
  u32 r;
  asm("v_cvt_pk_bf16_f32 %0, %1, %2" : "=v"(r) : "v"(lo), "v"(hi));
  return r;
}

// 2^x in one instruction
__device__ __forceinline__ float fexp2(float x) {
  float r;
  asm("v_exp_f32 %0, %1" : "=v"(r) : "v"(x));
  return r;
}

// f32 -> OCP e4m3 (RNE, flush <2^-6 to 0, clamp to 448).
__device__ __forceinline__ u32 f2e4m3(float f) {
  u32 u = __builtin_bit_cast(u32, f);
  const u32 s = (u >> 24) & 0x80u;
  const u32 au = u & 0x7fffffffu;
  if (au < 0x3c800000u) return s;           // |x| < 2^-6 -> signed zero
  if (au > 0x43e00000u) return s | 0x7eu;   // clamp to 448
  const u32 lsb = (au >> 20) & 1u;
  const u32 r = au + 0x0007ffffu + lsb;     // RNE to 3 mantissa bits
  const u32 e = (r >> 23) & 0xffu;
  const u32 m = (r >> 20) & 7u;
  return s | (((e - 120u) & 0xfu) << 3) | m;
}

// async global->LDS, 16B per lane; LDS dest is wave-uniform base + lane*16
__device__ __forceinline__ void gl_lds16(const void* g, void* l) {
  __builtin_amdgcn_global_load_lds(
      (const __attribute__((address_space(1))) void*)g,
      (__attribute__((address_space(3))) void*)l, 16, 0, 0);
}

// bijective XCD swizzle for grids with nwg % 8 == 0
__device__ __forceinline__ void xcd_swz(int GX, int GY, int& bx, int& by) {
  int flat = by * GX + bx;
  const int q = (GX * GY) >> 3;
  flat = (flat & 7) * q + (flat >> 3);
  bx = flat % GX;
  by = flat / GX;
}

// counted-vmcnt wait fused with barrier: single asm so the compiler cannot
// place any LDS read between the wait and the barrier (race prevention).
#define WAITB(N) asm volatile("s_waitcnt vmcnt(" #N ")\n\ts_barrier" ::: "memory")

// lgkm drain + scheduler fence (rule #18: keeps MFMA from hoisting past it)
#define LGKM0 do { asm volatile("s_waitcnt lgkmcnt(0)" ::: "memory"); \
                   __builtin_amdgcn_sched_barrier(0); } while (0)

// ---------------------------------------------------------------------------
// All weight transposes (+cast) in ONE kernel.  32x32 LDS tiles.
// ---------------------------------------------------------------------------
__global__ void prep_weights(const float* __restrict__ wq, const float* __restrict__ wk,
                             const float* __restrict__ wv, const float* __restrict__ wo,
                             const float* __restrict__ wg, const float* __restrict__ wu,
                             const float* __restrict__ wd,
                             u16* __restrict__ wqkv_t, u16* __restrict__ wo_t,
                             u8* __restrict__ wguf8, u16* __restrict__ wdn_t) {
  __shared__ float tile[32][33];
  const int id = blockIdx.x;
  const float* src;
  u16* dst = nullptr;
  int R, C, bx, by, mode;
  if (id < 3072) {
    const int which = id >> 10, lo = id & 1023;
    src = which == 0 ? wq : (which == 1 ? wk : wv);
    dst = wqkv_t + which * 1024 * 1024;
    R = 1024; C = 1024; bx = lo & 31; by = lo >> 5; mode = 0;
  } else if (id < 4096) {
    const int lo = id - 3072;
    src = wo; dst = wo_t; R = 1024; C = 1024; bx = lo & 31; by = lo >> 5; mode = 0;
  } else if (id < 8192) {
    const int lo = id - 4096;
    src = wg; R = 1024; C = 4096; bx = lo & 127; by = lo >> 7; mode = 1;
  } else if (id < 12288) {
    const int lo = id - 8192;
    src = wu; R = 1024; C = 4096; bx = lo & 127; by = lo >> 7; mode = 2;
  } else {
    const int lo = id - 12288;
    src = wd; dst = wdn_t; R = 4096; C = 1024; bx = lo & 31; by = lo >> 5; mode = 0;
  }
  const int tx = threadIdx.x, ty = threadIdx.y;
  const int c0 = bx * 32, r0 = by * 32;
#pragma unroll
  for (int i = 0; i < 4; i++)
    tile[ty + i * 8][tx] = src[(size_t)(r0 + ty + i * 8) * C + c0 + tx];
  __syncthreads();
  const int sx = ty * 32 + tx;
  const int oci = sx >> 3, cg = (sx & 7) * 4;
  const int oc = c0 + oci;
  const float v0 = tile[cg][oci], v1 = tile[cg + 1][oci];
  const float v2 = tile[cg + 2][oci], v3 = tile[cg + 3][oci];
  if (mode == 0) {
    uint2 o;
    o.x = (u32)f2bf(v0) | ((u32)f2bf(v1) << 16);
    o.y = (u32)f2bf(v2) | ((u32)f2bf(v3) << 16);
    *(uint2*)(dst + (size_t)oc * R + r0 + cg) = o;
  } else {
    const int orow = (oc >> 5) * 64 + (oc & 31) + (mode == 2 ? 32 : 0);
    const u32 p = f2e4m3(v0 * 64.f) | (f2e4m3(v1 * 64.f) << 8) |
                  (f2e4m3(v2 * 64.f) << 16) | (f2e4m3(v3 * 64.f) << 24);
    *(u32*)(wguf8 + (size_t)orow * 1024 + r0 + cg) = p;
  }
}

// ---------------------------------------------------------------------------
// RMSNorm: x [rows][1024] f32, g [1024] f32 -> bf16 (F8=0) or fp8 e4m3 (F8=1)
// ---------------------------------------------------------------------------
template <int F8>
__global__ __launch_bounds__(256) void rmsnorm_kernel(const float* __restrict__ x,
                                                      const float* __restrict__ g,
                                                      void* __restrict__ out) {
  const int row = blockIdx.x, t = threadIdx.x;
  const float4 v = ((const float4*)(x + (size_t)row * 1024))[t];
  float ss = v.x * v.x + v.y * v.y + v.z * v.z + v.w * v.w;
#pragma unroll
  for (int off = 32; off > 0; off >>= 1) ss += __shfl_xor(ss, off);
  __shared__ float red[4];
  if ((t & 63) == 0) red[t >> 6] = ss;
  __syncthreads();
  ss = red[0] + red[1] + red[2] + red[3];
  const float inv = rsqrtf(ss * (1.0f / 1024.0f) + 1e-6f);
  const float4 gv = ((const float4*)g)[t];
  const float y0 = v.x * inv * gv.x, y1 = v.y * inv * gv.y;
  const float y2 = v.z * inv * gv.z, y3 = v.w * inv * gv.w;
  if (F8) {
    const u32 p = f2e4m3(y0) | (f2e4m3(y1) << 8) | (f2e4m3(y2) << 16) | (f2e4m3(y3) << 24);
    ((u32*)out)[(size_t)row * 256 + t] = p;
  } else {
    uint2 o;
    o.x = (u32)f2bf(y0) | ((u32)f2bf(y1) << 16);
    o.y = (u32)f2bf(y2) | ((u32)f2bf(y3) << 16);
    ((uint2*)out)[(size_t)row * 256 + t] = o;
  }
}

// ---------------------------------------------------------------------------
// bf16 GEMM: C[M,N] = A[M,K] @ Bt[N,K]^T.  (unchanged from R4)
// ---------------------------------------------------------------------------
template <int BN>
__device__ __forceinline__ void bt_step(const u16* Asb, const u16* Bsb,
                                        floatx16 (&acc)[2][BN / 64],
                                        int wm, int wn, int c31, int khalf) {
  constexpr int NTI = BN / 64;
#pragma unroll
  for (int ks = 0; ks < 4; ks++) {
    bf16x8 af[2], bfr[NTI];
#pragma unroll
    for (int mi = 0; mi < 2; mi++) {
      const int row = wm * 64 + mi * 32 + c31;
      const int e = (ks * 2 + khalf) ^ (row & 7);
      af[mi] = *(const bf16x8*)(Asb + row * 64 + e * 8);
    }
#pragma unroll
    for (int ni = 0; ni < NTI; ni++) {
      const int row = wn * (BN / 2) + ni * 32 + c31;
      const int e = (ks * 2 + khalf) ^ (row & 7);
      bfr[ni] = *(const bf16x8*)(Bsb + row * 64 + e * 8);
    }
#pragma unroll
    for (int mi = 0; mi < 2; mi++)
#pragma unroll
      for (int ni = 0; ni < NTI; ni++)
        acc[mi][ni] = __builtin_amdgcn_mfma_f32_32x32x16_bf16(af[mi], bfr[ni],
                                                              acc[mi][ni], 0, 0, 0);
  }
}

template <int SPW>
__device__ __forceinline__ void bt_issue(const u16* (&gsrc)[SPW], u16* const (&ld0)[SPW],
                                         int bufofs) {
#pragma unroll
  for (int i = 0; i < SPW; i++) gl_lds16(gsrc[i], ld0[i] + bufofs);
#pragma unroll
  for (int i = 0; i < SPW; i++) gsrc[i] += 64;
}

template <int BN, int EPI>
__global__ __launch_bounds__(256) void gemm_bt(const u16* __restrict__ A,
                                               const u16* __restrict__ Bt,
                                               void* __restrict__ Cout,
                                               const float* __restrict__ res,
                                               u16* __restrict__ vTout,
                                               int M, int N, int K) {
  constexpr int NTI = BN / 64;        // n-subtiles of 32 per wave
  constexpr int ASZ = 128 * 64;       // u16 per buffer (A)
  constexpr int STRIDE = ASZ + BN * 64;  // u16 per buffer
  constexpr int NBUF = (BN == 64) ? 3 : 2;
  __shared__ u16 SMEM[NBUF * STRIDE];    // 72 KB (BN=64) / 64 KB (BN=128)
  constexpr int NSEG = 16 + BN / 8;   // 1024B staging segments
  constexpr int SPW = NSEG / 4;       // 6 (BN=64) or 8 (BN=128)
  const int t = threadIdx.x, w = t >> 6, l = t & 63;

  int bx = (int)blockIdx.x, by = (int)blockIdx.y;
  xcd_swz((int)gridDim.x, (int)gridDim.y, bx, by);
  const int m0 = by * 128, n0 = bx * BN;
  const int wm = w >> 1, wn = w & 1;
  const int c31 = l & 31, khalf = l >> 5;

  const u16* gsrc[SPW];
  u16* ld0[SPW];
  {
    const int rl = l >> 3, ch = (l & 7) ^ rl;
#pragma unroll
    for (int i = 0; i < SPW; i++) {
      const int s = w * SPW + i;
      if (s < 16) {
        gsrc[i] = A + (size_t)(m0 + s * 8 + rl) * K + ch * 8;
        ld0[i] = SMEM + s * 512;
      } else {
        gsrc[i] = Bt + (size_t)(n0 + (s - 16) * 8 + rl) * K + ch * 8;
        ld0[i] = SMEM + ASZ + (s - 16) * 512;
      }
    }
  }

  floatx16 acc[2][NTI] = {};

#define BT_STEP(CB) bt_step<BN>(SMEM + (CB)*STRIDE, SMEM + (CB)*STRIDE + ASZ, \
                                acc, wm, wn, c31, khalf)

  if constexpr (BN == 64) {
    // triple-buffer, depth-2, 1 fused wait+barrier per step
    bt_issue<SPW>(gsrc, ld0, 0 * STRIDE);
    bt_issue<SPW>(gsrc, ld0, 1 * STRIDE);
    const int NT = K >> 6;  // 16 or 64; both == 1 (mod 3), NT >= 7
    for (int rep = 0; rep < (NT - 4) / 3; rep++) {
      WAITB(6); bt_issue<SPW>(gsrc, ld0, 2 * STRIDE); BT_STEP(0);
      WAITB(6); bt_issue<SPW>(gsrc, ld0, 0 * STRIDE); BT_STEP(1);
      WAITB(6); bt_issue<SPW>(gsrc, ld0, 1 * STRIDE); BT_STEP(2);
    }
    WAITB(6); bt_issue<SPW>(gsrc, ld0, 2 * STRIDE); BT_STEP(0);   // tile NT-4
    WAITB(6); bt_issue<SPW>(gsrc, ld0, 0 * STRIDE); BT_STEP(1);   // tile NT-3
    WAITB(6); BT_STEP(2);                                         // tile NT-2
    WAITB(0); BT_STEP(0);                                         // tile NT-1
  } else {
    // 2-buffer, depth-1 counted: wait+barrier -> compute -> barrier -> reissue
    bt_issue<SPW>(gsrc, ld0, 0 * STRIDE);
    bt_issue<SPW>(gsrc, ld0, 1 * STRIDE);
    const int NT = K >> 6;  // even
    for (int kk = 0; kk < NT - 2; kk += 2) {
      WAITB(8); BT_STEP(0);
      __builtin_amdgcn_s_barrier();
      bt_issue<SPW>(gsrc, ld0, 0 * STRIDE);
      WAITB(8); BT_STEP(1);
      __builtin_amdgcn_s_barrier();
      bt_issue<SPW>(gsrc, ld0, 1 * STRIDE);
    }
    WAITB(8); BT_STEP(0);   // tile NT-2
    WAITB(0); BT_STEP(1);   // tile NT-1
  }
#undef BT_STEP

  // C/D layout (32x32): col = lane&31, row = (reg&3) + 8*(reg>>2) + 4*(lane>>5)
  if constexpr (EPI == 3) {
    if (n0 >= 2048) {
#pragma unroll
      for (int mi = 0; mi < 2; mi++)
#pragma unroll
        for (int ni = 0; ni < NTI; ni++) {
          const int col = n0 + wn * (BN / 2) + ni * 32 + c31 - 2048;
          const int hh = col >> 6, dv = col & 63;
          const int rbase = m0 + wm * 64 + mi * 32 + 4 * khalf;
          const int bb = rbase >> 11;
          u16* vp = vTout + (size_t)((bb * 16 + hh) * 64 + dv) * 2048 + (rbase & 2047);
#pragma unroll
          for (int rg = 0; rg < 4; rg++) {
            uint2 pk;
            pk.x = (u32)f2bf(acc[mi][ni][rg * 4 + 0]) |
                   ((u32)f2bf(acc[mi][ni][rg * 4 + 1]) << 16);
            pk.y = (u32)f2bf(acc[mi][ni][rg * 4 + 2]) |
                   ((u32)f2bf(acc[mi][ni][rg * 4 + 3]) << 16);
            *(uint2*)(vp + rg * 8) = pk;
          }
        }
      return;
    }
  }
#pragma unroll
  for (int mi = 0; mi < 2; mi++)
#pragma unroll
    for (int ni = 0; ni < NTI; ni++) {
      const int col = n0 + wn * (BN / 2) + ni * 32 + c31;
#pragma unroll
      for (int reg = 0; reg < 16; reg++) {
        const int row = m0 + wm * 64 + mi * 32 + (reg & 3) + 8 * (reg >> 2) + 4 * khalf;
        const size_t idx = (size_t)row * N + col;
        if (EPI == 1) ((float*)Cout)[idx] = acc[mi][ni][reg] + res[idx];
        else          ((u16*)Cout)[idx] = f2bf(acc[mi][ni][reg]);
      }
    }
}

// ---------------------------------------------------------------------------
// MX-fp8 gate/up GEMM — 8-wave fine-phased rewrite.
// hid = silu(h2 @ Wg) * (h2 @ Wu), fp8 e4m3, mfma_scale_f32_16x16x128_f8f6f4.
// Block 256(M) x 128(B-rows); 8 waves (4M x 2N); wave tile 64x64:
//   4 Msub x 4 Nsub 16x16 tiles, K-tile = 128 bytes -> 16 MFMA/wave/K-tile.
// LDS: ring of 3 regions x 48 KB (A 256x128B + B 128x128B) = 144 KB, 1 blk/CU.
//   Row-major [row][128B] with byte-offset XOR ((row&7)<<4): 2-way banks (free)
//   on ds_read_b128; staging pre-swizzles the GLOBAL source (rule #21), rows
//   8-lane-coalesced.  Depth-2 prefetch, vmcnt(6) at step heads (never 0
//   mid-loop).  Per K-tile: 2 phases, each {ds_read subtile || issue 3 stage
//   loads -> barrier -> lgkmcnt(0)+sched_barrier -> setprio(1) 8 MFMA
//   setprio(0) -> barrier}.
// Race-freedom: region (t+2)%3 is staged only after the step-t head barrier;
// every wave finished its step-(t-1) reads (lgkm0 before its MFMAs) before
// reaching that barrier, so no wave can still read the region being written.
// vmcnt is per-wave, but the fused wait+barrier means when ANY wave proceeds,
// ALL waves' loads for the tile have retired.
// ---------------------------------------------------------------------------
__device__ __forceinline__ i32x8 rd32(const u8* base, int r, int l4) {
  const int key = (r & 7) << 4;
  const uint4 lo = *(const uint4*)(base + r * 128 + ((l4 * 32) ^ key));
  const uint4 hi = *(const uint4*)(base + r * 128 + ((l4 * 32 + 16) ^ key));
  return i32x8{(int)lo.x, (int)lo.y, (int)lo.z, (int)lo.w,
               (int)hi.x, (int)hi.y, (int)hi.z, (int)hi.w};
}

__global__ __launch_bounds__(512) void gemm_f8(const u8* __restrict__ A,
                                               const u8* __restrict__ Bg,
                                               u16* __restrict__ hid,
                                               int M, int K) {
  constexpr int RSZ = 49152;          // 48 KB per ring region
  __shared__ u8 SMEM[3 * RSZ];        // 144 KB
  const int t = threadIdx.x, w = t >> 6, l = t & 63;
  int bx = (int)blockIdx.x, by = (int)blockIdx.y;
  xcd_swz((int)gridDim.x, (int)gridDim.y, bx, by);
  const int m0 = by * 256, n0 = bx * 128;
  const int wm = w >> 1, wn = w & 1;     // M quarter (64 rows) / B half (64 rows)
  const int l15 = l & 15, l4 = l >> 4;

  // staging: 48 segs of 1 KB (A: 32, B: 16); 6 per wave; seg = 8 rows x 128 B.
  // lane l covers row seg*8 + (l>>3), 16B chunk (l&7); global chunk pre-XORed
  // with (row&7) so the LDS-linear write realizes the swizzled layout.
  const u8* gsrc[6];
  u32 ldofs[6];
  {
    const int lr = l >> 3, ch = (l & 7) ^ lr;
#pragma unroll
    for (int i = 0; i < 6; i++) {
      const int s = w * 6 + i;
      if (s < 32) {
        gsrc[i] = A + (size_t)(m0 + s * 8 + lr) * (size_t)K + ch * 16;
        ldofs[i] = s * 1024u;
      } else {
        gsrc[i] = Bg + (size_t)(n0 + (s - 32) * 8 + lr) * (size_t)K + ch * 16;
        ldofs[i] = 32768u + (s - 32) * 1024u;
      }
    }
  }

  floatx4 acc[4][4] = {};
  i32x8 af[4], bf[4];

#define F8_ISSUE(SRHO, HALF)                                         \
  do {                                                               \
    _Pragma("unroll") for (int i = (HALF)*3; i < (HALF)*3 + 3; i++) { \
      gl_lds16(gsrc[i], SMEM + (SRHO)*RSZ + ldofs[i]);               \
      gsrc[i] += 128;                                                \
    }                                                                \
  } while (0)

#define F8_P0(RHO, SRHO, DOST)                                                 \
  do {                                                                         \
    const u8* Ra = SMEM + (RHO)*RSZ;                                           \
    const u8* Rb = Ra + 32768;                                                 \
    af[0] = rd32(Ra, wm * 64 + 0 * 16 + l15, l4);                              \
    af[1] = rd32(Ra, wm * 64 + 1 * 16 + l15, l4);                              \
    af[2] = rd32(Ra, wm * 64 + 2 * 16 + l15, l4);                              \
    af[3] = rd32(Ra, wm * 64 + 3 * 16 + l15, l4);                              \
    bf[0] = rd32(Rb, wn * 64 + 0 * 16 + l15, l4);                              \
    bf[1] = rd32(Rb, wn * 64 + 1 * 16 + l15, l4);                              \
    if (DOST) F8_ISSUE(SRHO, 0);                                               \
    __builtin_amdgcn_s_barrier();                                              \
    LGKM0;                                                                     \
    __builtin_amdgcn_s_setprio(1);                                             \
    _Pragma("unroll") for (int ms = 0; ms < 4; ms++)                           \
      _Pragma("unroll") for (int ns = 0; ns < 2; ns++)                         \
        acc[ms][ns] = __builtin_amdgcn_mfma_scale_f32_16x16x128_f8f6f4(        \
            af[ms], bf[ns], acc[ms][ns], 0, 0, 0, 0x7F7F7F7F, 0, 0x79797979);  \
    __builtin_amdgcn_s_setprio(0);                                             \
    __builtin_amdgcn_s_barrier();                                              \
  } while (0)

#define F8_P1(RHO, SRHO, DOST)                                                 \
  do {                                                                         \
    const u8* Rb = SMEM + (RHO)*RSZ + 32768;                                   \
    bf[2] = rd32(Rb, wn * 64 + 2 * 16 + l15, l4);                              \
    bf[3] = rd32(Rb, wn * 64 + 3 * 16 + l15, l4);                              \
    if (DOST) F8_ISSUE(SRHO, 1);                                               \
    __builtin_amdgcn_s_barrier();                                              \
    LGKM0;                                                                     \
    __builtin_amdgcn_s_setprio(1);                                             \
    _Pragma("unroll") for (int ms = 0; ms < 4; ms++)                           \
      _Pragma("unroll") for (int ns = 2; ns < 4; ns++)                         \
        acc[ms][ns] = __builtin_amdgcn_mfma_scale_f32_16x16x128_f8f6f4(        \
            af[ms], bf[ns], acc[ms][ns], 0, 0, 0, 0x7F7F7F7F, 0, 0x79797979);  \
    __builtin_amdgcn_s_setprio(0);                                             \
  } while (0)

  // prologue: tiles 0,1 into regions 0,1
  F8_ISSUE(0, 0); F8_ISSUE(0, 1);
  F8_ISSUE(1, 0); F8_ISSUE(1, 1);
  // K = 1024 -> 8 K-tiles of 128 B.  Stage t+2 during step t (depth 2).
  WAITB(6); F8_P0(0, 2, 1); F8_P1(0, 2, 1);   // t0, stage t2
  WAITB(6); F8_P0(1, 0, 1); F8_P1(1, 0, 1);   // t1, stage t3
  WAITB(6); F8_P0(2, 1, 1); F8_P1(2, 1, 1);   // t2, stage t4
  WAITB(6); F8_P0(0, 2, 1); F8_P1(0, 2, 1);   // t3, stage t5
  WAITB(6); F8_P0(1, 0, 1); F8_P1(1, 0, 1);   // t4, stage t6
  WAITB(6); F8_P0(2, 1, 1); F8_P1(2, 1, 1);   // t5, stage t7
  WAITB(6); F8_P0(0, 0, 0); F8_P1(0, 0, 0);   // t6
  WAITB(0); F8_P0(1, 0, 0); F8_P1(1, 0, 0);   // t7
#undef F8_P0
#undef F8_P1
#undef F8_ISSUE

  // epilogue: C/D 16x16: col = lane&15, row = (lane>>4)*4 + reg.
  // acc[ms][n]: n 0..1 = gate cols, n 2..3 = up cols of group G.
  const int G = bx * 2 + wn;
#pragma unroll
  for (int ms = 0; ms < 4; ms++)
#pragma unroll
    for (int np = 0; np < 2; np++)
#pragma unroll
      for (int reg = 0; reg < 4; reg++) {
        const int row = m0 + wm * 64 + ms * 16 + l4 * 4 + reg;
        const int col = G * 32 + np * 16 + l15;
        const float g = acc[ms][np][reg];
        const float u = acc[ms][np + 2][reg];
        hid[(size_t)row * 4096 + col] = f2bf(g / (1.f + __expf(-g)) * u);
      }
}

// ---------------------------------------------------------------------------
// Causal attention (strict k<q), softmax = exp(s)/(sum+1e-9), flash-style.
// (unchanged from R4)
// ---------------------------------------------------------------------------
__global__ __launch_bounds__(256) void attn_kernel(const u16* __restrict__ qkv,
                                                   const u16* __restrict__ vT,
                                                   u16* __restrict__ av) {
  __shared__ u16 SM[2 * 8192];
  __shared__ u16 Ps[4 * 2048];
  const int t = threadIdx.x, w = t >> 6, l = t & 63;
  const int lrow = l & 15, lk = l >> 4;
  const int bh = blockIdx.x;
  const int b = bh >> 4, h = bh & 15;
  const int qt = 15 - (int)blockIdx.y;
  const int qbase = qt * 128 + w * 32;
  const int ktmax = 2 * qt + 1;
  u16* Pw = Ps + w * 2048;
  const float SC = 0.125f * 1.44269504088896f;  // log2(e)/8

  bf16x8 aq[2][2];
#pragma unroll
  for (int sub = 0; sub < 2; sub++)
#pragma unroll
    for (int half = 0; half < 2; half++)
      aq[sub][half] = *(const bf16x8*)(qkv + (size_t)(b * S_ + qbase + sub * 16 + lrow) * 3072 +
                                       h * 64 + half * 32 + lk * 8);

  const u16* gcur[4];
  int gstep[4], loff[4];
#pragma unroll
  for (int i = 0; i < 4; i++) {
    const int c = w + 4 * i;
    const int half = (c >> 2) & 1, grp = c & 3;
    if (c < 8) {
      gcur[i] = qkv + (size_t)(b * S_ + grp * 16 + (l >> 2)) * 3072 + D_ + h * 64 +
                half * 32 + (l & 3) * 8;
      gstep[i] = 64 * 3072;
      loff[i] = half * 2048 + grp * 512;
    } else {
      gcur[i] = vT + (size_t)(bh * 64 + grp * 16 + (l >> 2)) * S_ + half * 32 + (l & 3) * 8;
      gstep[i] = 64;
      loff[i] = 4096 + half * 2048 + grp * 512;
    }
  }

  floatx4 oacc[2][4] = {};
  float den[2] = {0.f, 0.f};

  int cur = 0;
#pragma unroll
  for (int i = 0; i < 4; i++) { gl_lds16(gcur[i], SM + loff[i]); gcur[i] += gstep[i]; }

  for (int kt = 0; kt <= ktmax; kt++) {
    __syncthreads();
    if (kt < ktmax) {
#pragma unroll
      for (int i = 0; i < 4; i++) {
        gl_lds16(gcur[i], SM + (cur ^ 1) * 8192 + loff[i]);
        gcur[i] += gstep[i];
      }
    }
    const u16* Kbuf = SM + cur * 8192;
    const u16* Vbuf = Kbuf + 4096;

    // wave-uniform tile classification vs this wave's q rows [qbase, qbase+32)
    const bool active = (kt * 64 < qbase + 31);    // some k < some q
    if (active) {
      const bool need_mask = (kt * 64 + 64 > qbase);  // tile straddles diagonal

      bf16x8 bk[4][2];
#pragma unroll
      for (int ct = 0; ct < 4; ct++)
#pragma unroll
        for (int half = 0; half < 2; half++)
          bk[ct][half] = *(const bf16x8*)(Kbuf + half * 2048 + (ct * 16 + lrow) * 32 + lk * 8);

      floatx4 sf[2][4] = {};
      __builtin_amdgcn_s_setprio(1);
#pragma unroll
      for (int sub = 0; sub < 2; sub++)
#pragma unroll
        for (int ct = 0; ct < 4; ct++) {
          sf[sub][ct] = __builtin_amdgcn_mfma_f32_16x16x32_bf16(bk[ct][0], aq[sub][0],
                                                                sf[sub][ct], 0, 0, 0);
          sf[sub][ct] = __builtin_amdgcn_mfma_f32_16x16x32_bf16(bk[ct][1], aq[sub][1],
                                                                sf[sub][ct], 0, 0, 0);
        }
      __builtin_amdgcn_s_setprio(0);

      if (!need_mask) {
        // fast path: every k in tile < every q of this wave
#pragma unroll
        for (int sub = 0; sub < 2; sub++) {
          const int prow = sub * 16 + lrow;
#pragma unroll
          for (int ct = 0; ct < 4; ct++) {
            const float p0 = fexp2(sf[sub][ct][0] * SC);
            const float p1 = fexp2(sf[sub][ct][1] * SC);
            const float p2 = fexp2(sf[sub][ct][2] * SC);
            const float p3 = fexp2(sf[sub][ct][3] * SC);
            den[sub] += (p0 + p1) + (p2 + p3);
            uint2 pk;
            pk.x = cvtpk_bf16(p0, p1);
            pk.y = cvtpk_bf16(p2, p3);
            *(uint2*)(Pw + prow * 64 + (((2 * ct + (lk >> 1)) ^ (lrow & 7)) << 3) +
                      (lk & 1) * 4) = pk;
          }
        }
      } else {
#pragma unroll
        for (int sub = 0; sub < 2; sub++) {
          const int qp = qbase + sub * 16 + lrow;
          const int prow = sub * 16 + lrow;
#pragma unroll
          for (int ct = 0; ct < 4; ct++) {
            const int kb = kt * 64 + ct * 16 + lk * 4;
            const float p0 = (kb + 0 < qp) ? fexp2(sf[sub][ct][0] * SC) : 0.f;
            const float p1 = (kb + 1 < qp) ? fexp2(sf[sub][ct][1] * SC) : 0.f;
            const float p2 = (kb + 2 < qp) ? fexp2(sf[sub][ct][2] * SC) : 0.f;
            const float p3 = (kb + 3 < qp) ? fexp2(sf[sub][ct][3] * SC) : 0.f;
            den[sub] += (p0 + p1) + (p2 + p3);
            uint2 pk;
            pk.x = cvtpk_bf16(p0, p1);
            pk.y = cvtpk_bf16(p2, p3);
            *(uint2*)(Pw + prow * 64 + (((2 * ct + (lk >> 1)) ^ (lrow & 7)) << 3) +
                      (lk & 1) * 4) = pk;
          }
        }
      }

      bf16x8 ap[2][2], bv[4][2];
#pragma unroll
      for (int sub = 0; sub < 2; sub++)
#pragma unroll
        for (int kh = 0; kh < 2; kh++) {
          const int prow = sub * 16 + lrow;
          ap[sub][kh] = *(const bf16x8*)(Pw + prow * 64 + (((kh * 4 + lk) ^ (prow & 7)) << 3));
        }
#pragma unroll
      for (int ni = 0; ni < 4; ni++)
#pragma unroll
        for (int kh = 0; kh < 2; kh++)
          bv[ni][kh] = *(const bf16x8*)(Vbuf + kh * 2048 + (ni * 16 + lrow) * 32 + lk * 8);
      __builtin_amdgcn_s_setprio(1);
#pragma unroll
      for (int sub = 0; sub < 2; sub++)
#pragma unroll
        for (int ni = 0; ni < 4; ni++) {
          oacc[sub][ni] = __builtin_amdgcn_mfma_f32_16x16x32_bf16(ap[sub][0], bv[ni][0],
                                                                  oacc[sub][ni], 0, 0, 0);
          oacc[sub][ni] = __builtin_amdgcn_mfma_f32_16x16x32_bf16(ap[sub][1], bv[ni][1],
                                                                  oacc[sub][ni], 0, 0, 0);
        }
      __builtin_amdgcn_s_setprio(0);
    }
    cur ^= 1;
  }

#pragma unroll
  for (int sub = 0; sub < 2; sub++) {
    den[sub] += __shfl_xor(den[sub], 16);
    den[sub] += __shfl_xor(den[sub], 32);
  }
  float dq[2][4];
#pragma unroll
  for (int sub = 0; sub < 2; sub++)
#pragma unroll
    for (int r = 0; r < 4; r++)
      dq[sub][r] = __shfl(den[sub], lk * 4 + r);

#pragma unroll
  for (int sub = 0; sub < 2; sub++)
#pragma unroll
    for (int ni = 0; ni < 4; ni++)
#pragma unroll
      for (int r = 0; r < 4; r++) {
        const int row = qbase + sub * 16 + lk * 4 + r;
        const int col = h * 64 + ni * 16 + lrow;
        av[(size_t)(b * S_ + row) * 1024 + col] = f2bf(oacc[sub][ni][r] / (dq[sub][r] + 1e-9f));
      }
}

// ---------------------------------------------------------------------------
// Workspace layout (bytes)
// ---------------------------------------------------------------------------
#define OFF_WQKV 0u            // [3072][1024] bf16
#define OFF_WO   6291456u      // [1024][1024] bf16
#define OFF_WGU8 8388608u      // [8192][1024] fp8 (gate/up 32-col interleaved, x64)
#define OFF_WDN  16777216u     // [1024][4096] bf16
#define OFF_H1   25165824u     // [4096][1024] bf16
#define OFF_QKV  33554432u     // [4096][3072] bf16 (V region unused)
#define OFF_VT   58720256u     // [2][16][64][2048] bf16
#define OFF_AV   67108864u     // [4096][1024] bf16
#define OFF_X1   75497472u     // [4096][1024] f32
#define OFF_H2F8 92274688u     // [4096][1024] fp8
#define OFF_HID  96468992u     // [4096][4096] bf16

extern "C" void kernel_launch(void* const* d_in, const int* in_sizes, int n_in,
                              void* d_out, int out_size, void* d_ws, size_t ws_size,
                              hipStream_t stream) {
  const float* x      = (const float*)d_in[0];
  const float* w_q    = (const float*)d_in[1];
  const float* w_k    = (const float*)d_in[2];
  const float* w_v    = (const float*)d_in[3];
  const float* w_o    = (const float*)d_in[4];
  const float* w_gate = (const float*)d_in[5];
  const float* w_up   = (const float*)d_in[6];
  const float* w_down = (const float*)d_in[7];
  const float* g1     = (const float*)d_in[8];
  const float* g2     = (const float*)d_in[9];

  char* ws = (char*)d_ws;
  u16* wqkv_t = (u16*)(ws + OFF_WQKV);
  u16* wo_t   = (u16*)(ws + OFF_WO);
  u8*  wguf8  = (u8*)(ws + OFF_WGU8);
  u16* wdn_t  = (u16*)(ws + OFF_WDN);
  u16* h1     = (u16*)(ws + OFF_H1);
  u16* qkv    = (u16*)(ws + OFF_QKV);
  u16* vT     = (u16*)(ws + OFF_VT);
  u16* av     = (u16*)(ws + OFF_AV);
  float* x1   = (float*)(ws + OFF_X1);
  u8*  h2f8   = (u8*)(ws + OFF_H2F8);
  u16* hid    = (u16*)(ws + OFF_HID);
  float* out  = (float*)d_out;

  prep_weights<<<16384, dim3(32, 8), 0, stream>>>(w_q, w_k, w_v, w_o, w_gate, w_up, w_down,
                                                  wqkv_t, wo_t, wguf8, wdn_t);

  rmsnorm_kernel<0><<<BS_, 256, 0, stream>>>(x, g1, h1);
  // qkv GEMM: BN=128 (wave tile 64x64), 2-buf counted pipe; V blocks -> vT
  gemm_bt<128, 3><<<dim3(3072 / 128, BS_ / 128), 256, 0, stream>>>(
      h1, wqkv_t, qkv, nullptr, vT, BS_, 3072, 1024);
  attn_kernel<<<dim3(32, 16), 256, 0, stream>>>(qkv, vT, av);
  gemm_bt<64, 1><<<dim3(1024 / 64, BS_ / 128), 256, 0, stream>>>(
      av, wo_t, x1, x, nullptr, BS_, 1024, 1024);
  rmsnorm_kernel<1><<<BS_, 256, 0, stream>>>(x1, g2, h2f8);
  // fused gate/up GEMM in MX-fp8: 8-wave fine-phased, block 256x128
  gemm_f8<<<dim3(8192 / 128, BS_ / 256), 512, 0, stream>>>(h2f8, wguf8, hid, BS_, 1024);
  gemm_bt<64, 1><<<dim3(1024 / 64, BS_ / 128), 256, 0, stream>>>(
      hid, wdn_t, out, x1, nullptr, BS_, 1024, 4096);
}

// Round 6
// 336.068 us; speedup vs baseline: 1.0363x; 1.0363x over previous
//
#include <hip/hip_runtime.h>
#include <cstdint>
#include <cstddef>

typedef unsigned short u16;
typedef unsigned char u8;
typedef unsigned int u32;
typedef __bf16 bf16x8 __attribute__((ext_vector_type(8)));
typedef float floatx4 __attribute__((ext_vector_type(4)));
typedef float floatx16 __attribute__((ext_vector_type(16)));
typedef int i32x8 __attribute__((ext_vector_type(8)));

#define B_ 2
#define S_ 2048
#define D_ 1024
#define H_ 16
#define DFF_ 4096
#define BS_ 4096   // B_*S_

__device__ __forceinline__ u16 f2bf(float f) {
  u32 u = __builtin_bit_cast(u32, f);
  u += 0x7fffu + ((u >> 16) & 1u);
  return (u16)(u >> 16);
}
__device__ __forceinline__ float bf2f(u16 h) {
  u32 u = ((u32)h) << 16;
  return __builtin_bit_cast(float, u);
}

// packed f32x2 -> bf16x2 (RNE), single instruction
__device__ __forceinline__ u32 cvtpk_bf16(float lo, float hi) {
  u32 r;
  asm("v_cvt_pk_bf16_f32 %0, %1, %2" : "=v"(r) : "v"(lo), "v"(hi));
  return r;
}

// 2^x in one instruction
__device__ __forceinline__ float fexp2(float x) {
  float r;
  asm("v_exp_f32 %0, %1" : "=v"(r) : "v"(x));
  return r;
}

// f32 -> OCP e4m3 (RNE, flush <2^-6 to 0, clamp to 448).
__device__ __forceinline__ u32 f2e4m3(float f) {
  u32 u = __builtin_bit_cast(u32, f);
  const u32 s = (u >> 24) & 0x80u;
  const u32 au = u & 0x7fffffffu;
  if (au < 0x3c800000u) return s;           // |x| < 2^-6 -> signed zero
  if (au > 0x43e00000u) return s | 0x7eu;   // clamp to 448
  const u32 lsb = (au >> 20) & 1u;
  const u32 r = au + 0x0007ffffu + lsb;     // RNE to 3 mantissa bits
  const u32 e = (r >> 23) & 0xffu;
  const u32 m = (r >> 20) & 7u;
  return s | (((e - 120u) & 0xfu) << 3) | m;
}

// async global->LDS, 16B per lane; LDS dest is wave-uniform base + lane*16
__device__ __forceinline__ void gl_lds16(const void* g, void* l) {
  __builtin_amdgcn_global_load_lds(
      (const __attribute__((address_space(1))) void*)g,
      (__attribute__((address_space(3))) void*)l, 16, 0, 0);
}

// bijective XCD swizzle for grids with nwg % 8 == 0
__device__ __forceinline__ void xcd_swz(int GX, int GY, int& bx, int& by) {
  int flat = by * GX + bx;
  const int q = (GX * GY) >> 3;
  flat = (flat & 7) * q + (flat >> 3);
  bx = flat % GX;
  by = flat / GX;
}

// counted-vmcnt wait fused with barrier: single asm so the compiler cannot
// place any LDS read between the wait and the barrier (race prevention).
#define WAITB(N) asm volatile("s_waitcnt vmcnt(" #N ")\n\ts_barrier" ::: "memory")

// ---------------------------------------------------------------------------
// All weight transposes (+cast) in ONE kernel.  32x32 LDS tiles.
// ---------------------------------------------------------------------------
__global__ void prep_weights(const float* __restrict__ wq, const float* __restrict__ wk,
                             const float* __restrict__ wv, const float* __restrict__ wo,
                             const float* __restrict__ wg, const float* __restrict__ wu,
                             const float* __restrict__ wd,
                             u16* __restrict__ wqkv_t, u16* __restrict__ wo_t,
                             u8* __restrict__ wguf8, u16* __restrict__ wdn_t) {
  __shared__ float tile[32][33];
  const int id = blockIdx.x;
  const float* src;
  u16* dst = nullptr;
  int R, C, bx, by, mode;
  if (id < 3072) {
    const int which = id >> 10, lo = id & 1023;
    src = which == 0 ? wq : (which == 1 ? wk : wv);
    dst = wqkv_t + which * 1024 * 1024;
    R = 1024; C = 1024; bx = lo & 31; by = lo >> 5; mode = 0;
  } else if (id < 4096) {
    const int lo = id - 3072;
    src = wo; dst = wo_t; R = 1024; C = 1024; bx = lo & 31; by = lo >> 5; mode = 0;
  } else if (id < 8192) {
    const int lo = id - 4096;
    src = wg; R = 1024; C = 4096; bx = lo & 127; by = lo >> 7; mode = 1;
  } else if (id < 12288) {
    const int lo = id - 8192;
    src = wu; R = 1024; C = 4096; bx = lo & 127; by = lo >> 7; mode = 2;
  } else {
    const int lo = id - 12288;
    src = wd; dst = wdn_t; R = 4096; C = 1024; bx = lo & 31; by = lo >> 5; mode = 0;
  }
  const int tx = threadIdx.x, ty = threadIdx.y;
  const int c0 = bx * 32, r0 = by * 32;
#pragma unroll
  for (int i = 0; i < 4; i++)
    tile[ty + i * 8][tx] = src[(size_t)(r0 + ty + i * 8) * C + c0 + tx];
  __syncthreads();
  const int sx = ty * 32 + tx;
  const int oci = sx >> 3, cg = (sx & 7) * 4;
  const int oc = c0 + oci;
  const float v0 = tile[cg][oci], v1 = tile[cg + 1][oci];
  const float v2 = tile[cg + 2][oci], v3 = tile[cg + 3][oci];
  if (mode == 0) {
    uint2 o;
    o.x = (u32)f2bf(v0) | ((u32)f2bf(v1) << 16);
    o.y = (u32)f2bf(v2) | ((u32)f2bf(v3) << 16);
    *(uint2*)(dst + (size_t)oc * R + r0 + cg) = o;
  } else {
    const int orow = (oc >> 5) * 64 + (oc & 31) + (mode == 2 ? 32 : 0);
    const u32 p = f2e4m3(v0 * 64.f) | (f2e4m3(v1 * 64.f) << 8) |
                  (f2e4m3(v2 * 64.f) << 16) | (f2e4m3(v3 * 64.f) << 24);
    *(u32*)(wguf8 + (size_t)orow * 1024 + r0 + cg) = p;
  }
}

// ---------------------------------------------------------------------------
// RMSNorm: x [rows][1024] f32, g [1024] f32 -> bf16 (F8=0) or fp8 e4m3 (F8=1).
// F8=1 writes FRAGMENT-MAJOR layout A'[(r>>5)*16 + (k>>6)][lane=(k>>5 &1)*32
// + (r&31)][32B]: a 32x32x64 MFMA A-fragment is one contiguous 2KB block,
// lane l at offset l*32 -> gemm_f8 loads A directly to VGPRs (no LDS).
// ---------------------------------------------------------------------------
template <int F8>
__global__ __launch_bounds__(256) void rmsnorm_kernel(const float* __restrict__ x,
                                                      const float* __restrict__ g,
                                                      void* __restrict__ out) {
  const int row = blockIdx.x, t = threadIdx.x;
  const float4 v = ((const float4*)(x + (size_t)row * 1024))[t];
  float ss = v.x * v.x + v.y * v.y + v.z * v.z + v.w * v.w;
#pragma unroll
  for (int off = 32; off > 0; off >>= 1) ss += __shfl_xor(ss, off);
  __shared__ float red[4];
  if ((t & 63) == 0) red[t >> 6] = ss;
  __syncthreads();
  ss = red[0] + red[1] + red[2] + red[3];
  const float inv = rsqrtf(ss * (1.0f / 1024.0f) + 1e-6f);
  const float4 gv = ((const float4*)g)[t];
  const float y0 = v.x * inv * gv.x, y1 = v.y * inv * gv.y;
  const float y2 = v.z * inv * gv.z, y3 = v.w * inv * gv.w;
  if (F8) {
    const u32 p = f2e4m3(y0) | (f2e4m3(y1) << 8) | (f2e4m3(y2) << 16) | (f2e4m3(y3) << 24);
    const int k = t * 4;
    const u32 ofs = (u32)(((row >> 5) * 16 + (k >> 6)) * 2048 +
                          ((k >> 5) & 1) * 1024 + (row & 31) * 32 + (k & 31));
    *(u32*)((u8*)out + ofs) = p;
  } else {
    uint2 o;
    o.x = (u32)f2bf(y0) | ((u32)f2bf(y1) << 16);
    o.y = (u32)f2bf(y2) | ((u32)f2bf(y3) << 16);
    ((uint2*)out)[(size_t)row * 256 + t] = o;
  }
}

// ---------------------------------------------------------------------------
// bf16 GEMM: C[M,N] = A[M,K] @ Bt[N,K]^T.  (unchanged from R4)
// ---------------------------------------------------------------------------
template <int BN>
__device__ __forceinline__ void bt_step(const u16* Asb, const u16* Bsb,
                                        floatx16 (&acc)[2][BN / 64],
                                        int wm, int wn, int c31, int khalf) {
  constexpr int NTI = BN / 64;
#pragma unroll
  for (int ks = 0; ks < 4; ks++) {
    bf16x8 af[2], bfr[NTI];
#pragma unroll
    for (int mi = 0; mi < 2; mi++) {
      const int row = wm * 64 + mi * 32 + c31;
      const int e = (ks * 2 + khalf) ^ (row & 7);
      af[mi] = *(const bf16x8*)(Asb + row * 64 + e * 8);
    }
#pragma unroll
    for (int ni = 0; ni < NTI; ni++) {
      const int row = wn * (BN / 2) + ni * 32 + c31;
      const int e = (ks * 2 + khalf) ^ (row & 7);
      bfr[ni] = *(const bf16x8*)(Bsb + row * 64 + e * 8);
    }
#pragma unroll
    for (int mi = 0; mi < 2; mi++)
#pragma unroll
      for (int ni = 0; ni < NTI; ni++)
        acc[mi][ni] = __builtin_amdgcn_mfma_f32_32x32x16_bf16(af[mi], bfr[ni],
                                                              acc[mi][ni], 0, 0, 0);
  }
}

template <int SPW>
__device__ __forceinline__ void bt_issue(const u16* (&gsrc)[SPW], u16* const (&ld0)[SPW],
                                         int bufofs) {
#pragma unroll
  for (int i = 0; i < SPW; i++) gl_lds16(gsrc[i], ld0[i] + bufofs);
#pragma unroll
  for (int i = 0; i < SPW; i++) gsrc[i] += 64;
}

template <int BN, int EPI>
__global__ __launch_bounds__(256) void gemm_bt(const u16* __restrict__ A,
                                               const u16* __restrict__ Bt,
                                               void* __restrict__ Cout,
                                               const float* __restrict__ res,
                                               u16* __restrict__ vTout,
                                               int M, int N, int K) {
  constexpr int NTI = BN / 64;        // n-subtiles of 32 per wave
  constexpr int ASZ = 128 * 64;       // u16 per buffer (A)
  constexpr int STRIDE = ASZ + BN * 64;  // u16 per buffer
  constexpr int NBUF = (BN == 64) ? 3 : 2;
  __shared__ u16 SMEM[NBUF * STRIDE];    // 72 KB (BN=64) / 64 KB (BN=128)
  constexpr int NSEG = 16 + BN / 8;   // 1024B staging segments
  constexpr int SPW = NSEG / 4;       // 6 (BN=64) or 8 (BN=128)
  const int t = threadIdx.x, w = t >> 6, l = t & 63;

  int bx = (int)blockIdx.x, by = (int)blockIdx.y;
  xcd_swz((int)gridDim.x, (int)gridDim.y, bx, by);
  const int m0 = by * 128, n0 = bx * BN;
  const int wm = w >> 1, wn = w & 1;
  const int c31 = l & 31, khalf = l >> 5;

  const u16* gsrc[SPW];
  u16* ld0[SPW];
  {
    const int rl = l >> 3, ch = (l & 7) ^ rl;
#pragma unroll
    for (int i = 0; i < SPW; i++) {
      const int s = w * SPW + i;
      if (s < 16) {
        gsrc[i] = A + (size_t)(m0 + s * 8 + rl) * K + ch * 8;
        ld0[i] = SMEM + s * 512;
      } else {
        gsrc[i] = Bt + (size_t)(n0 + (s - 16) * 8 + rl) * K + ch * 8;
        ld0[i] = SMEM + ASZ + (s - 16) * 512;
      }
    }
  }

  floatx16 acc[2][NTI] = {};

#define BT_STEP(CB) bt_step<BN>(SMEM + (CB)*STRIDE, SMEM + (CB)*STRIDE + ASZ, \
                                acc, wm, wn, c31, khalf)

  if constexpr (BN == 64) {
    // triple-buffer, depth-2, 1 fused wait+barrier per step
    bt_issue<SPW>(gsrc, ld0, 0 * STRIDE);
    bt_issue<SPW>(gsrc, ld0, 1 * STRIDE);
    const int NT = K >> 6;  // 16 or 64; both == 1 (mod 3), NT >= 7
    for (int rep = 0; rep < (NT - 4) / 3; rep++) {
      WAITB(6); bt_issue<SPW>(gsrc, ld0, 2 * STRIDE); BT_STEP(0);
      WAITB(6); bt_issue<SPW>(gsrc, ld0, 0 * STRIDE); BT_STEP(1);
      WAITB(6); bt_issue<SPW>(gsrc, ld0, 1 * STRIDE); BT_STEP(2);
    }
    WAITB(6); bt_issue<SPW>(gsrc, ld0, 2 * STRIDE); BT_STEP(0);   // tile NT-4
    WAITB(6); bt_issue<SPW>(gsrc, ld0, 0 * STRIDE); BT_STEP(1);   // tile NT-3
    WAITB(6); BT_STEP(2);                                         // tile NT-2
    WAITB(0); BT_STEP(0);                                         // tile NT-1
  } else {
    // 2-buffer, depth-1 counted: wait+barrier -> compute -> barrier -> reissue
    bt_issue<SPW>(gsrc, ld0, 0 * STRIDE);
    bt_issue<SPW>(gsrc, ld0, 1 * STRIDE);
    const int NT = K >> 6;  // even
    for (int kk = 0; kk < NT - 2; kk += 2) {
      WAITB(8); BT_STEP(0);
      __builtin_amdgcn_s_barrier();
      bt_issue<SPW>(gsrc, ld0, 0 * STRIDE);
      WAITB(8); BT_STEP(1);
      __builtin_amdgcn_s_barrier();
      bt_issue<SPW>(gsrc, ld0, 1 * STRIDE);
    }
    WAITB(8); BT_STEP(0);   // tile NT-2
    WAITB(0); BT_STEP(1);   // tile NT-1
  }
#undef BT_STEP

  // C/D layout (32x32): col = lane&31, row = (reg&3) + 8*(reg>>2) + 4*(lane>>5)
  if constexpr (EPI == 3) {
    if (n0 >= 2048) {
#pragma unroll
      for (int mi = 0; mi < 2; mi++)
#pragma unroll
        for (int ni = 0; ni < NTI; ni++) {
          const int col = n0 + wn * (BN / 2) + ni * 32 + c31 - 2048;
          const int hh = col >> 6, dv = col & 63;
          const int rbase = m0 + wm * 64 + mi * 32 + 4 * khalf;
          const int bb = rbase >> 11;
          u16* vp = vTout + (size_t)((bb * 16 + hh) * 64 + dv) * 2048 + (rbase & 2047);
#pragma unroll
          for (int rg = 0; rg < 4; rg++) {
            uint2 pk;
            pk.x = (u32)f2bf(acc[mi][ni][rg * 4 + 0]) |
                   ((u32)f2bf(acc[mi][ni][rg * 4 + 1]) << 16);
            pk.y = (u32)f2bf(acc[mi][ni][rg * 4 + 2]) |
                   ((u32)f2bf(acc[mi][ni][rg * 4 + 3]) << 16);
            *(uint2*)(vp + rg * 8) = pk;
          }
        }
      return;
    }
  }
#pragma unroll
  for (int mi = 0; mi < 2; mi++)
#pragma unroll
    for (int ni = 0; ni < NTI; ni++) {
      const int col = n0 + wn * (BN / 2) + ni * 32 + c31;
#pragma unroll
      for (int reg = 0; reg < 16; reg++) {
        const int row = m0 + wm * 64 + mi * 32 + (reg & 3) + 8 * (reg >> 2) + 4 * khalf;
        const size_t idx = (size_t)row * N + col;
        if (EPI == 1) ((float*)Cout)[idx] = acc[mi][ni][reg] + res[idx];
        else          ((u16*)Cout)[idx] = f2bf(acc[mi][ni][reg]);
      }
    }
}

// ---------------------------------------------------------------------------
// MX-fp8 gate/up GEMM: hid = silu(h2 @ Wg) * (h2 @ Wu).
// Block 128x128 B-rows, 4 waves 2x2, wave tile 64x64, mfma 32x32x64.
// NEW: A comes from the fragment-major A' (rmsnorm<1>) DIRECTLY to VGPRs —
//   one contiguous 2KB coalesced read per fragment, no LDS for A.
//   LDS = B-only ring of 3 x 8KB = 24 KB -> 6 blocks/CU.
// NEW: L2-tiled XCD traversal: each XCD walks (bxg 4 groups)x(4 by)x(16 bx)
//   so the L2 working set is B-slice 2MB + A 0.5MB (was 10MB, thrashing).
// Triple-buffer depth-2 counted vmcnt(6) = 4 A-loads + 2 B-stages per body.
// ---------------------------------------------------------------------------
__global__ __launch_bounds__(256) void gemm_f8(const u8* __restrict__ Af,
                                               const u8* __restrict__ Bg,
                                               u16* __restrict__ hid,
                                               int M, int K) {
  constexpr int BSZ = 8192;           // 8 KB per B ring slot
  __shared__ u8 SMEM[3 * BSZ];        // 24 KB
  const int t = threadIdx.x, w = t >> 6, l = t & 63;
  // L2-tiled traversal: GX=64, GY=32, 2048 blocks, 256 per XCD.
  int bx, by;
  {
    const int flat = (int)blockIdx.y * 64 + (int)blockIdx.x;
    const int xcd = flat & 7, seq = flat >> 3;              // 0..255
    const int bxl = seq & 15, byl = (seq >> 4) & 3, bxg = seq >> 6;
    bx = bxg * 16 + bxl;
    by = xcd * 4 + byl;
  }
  const int m0 = by * 128, n0 = bx * 128;
  const int wm = w >> 1, wn = w & 1;
  const int c31 = l & 31, hf = l >> 5;

  // B staging: 8 segs of 1KB (16 rows x 64B), 2 per wave; XOR chunk swizzle
  const u8* gsrcB[2];
  u32 ldofsB[2];
  {
    const int rl = l >> 2, ch = (l & 3) ^ ((l >> 3) & 3);
#pragma unroll
    for (int i = 0; i < 2; i++) {
      const int s = w * 2 + i;
      gsrcB[i] = Bg + (size_t)(n0 + s * 16 + rl) * K + ch * 16;
      ldofsB[i] = (u32)(s * 1024);
    }
  }
  // A fragment pointers: rowgrp g = by*4 + wm*2 + mi; frag(t) at (g*16+t)*2048,
  // lane l at +l*32.  Advanced +2048 per issued tile.
  const u8* Acur[2];
#pragma unroll
  for (int mi = 0; mi < 2; mi++)
    Acur[mi] = Af + (size_t)((by * 4 + wm * 2 + mi) * 16) * 2048 + l * 32;

  floatx16 acc[2][2] = {};
  i32x8 afr[3][2];

#define F8_LDA(SL)                                                      \
  do {                                                                  \
    _Pragma("unroll") for (int mi = 0; mi < 2; mi++) {                  \
      const uint4 lo = *(const uint4*)(Acur[mi]);                       \
      const uint4 hi = *(const uint4*)(Acur[mi] + 16);                  \
      afr[SL][mi] = i32x8{(int)lo.x, (int)lo.y, (int)lo.z, (int)lo.w,   \
                          (int)hi.x, (int)hi.y, (int)hi.z, (int)hi.w};  \
      Acur[mi] += 2048;                                                 \
    }                                                                   \
  } while (0)

#define F8_STB(SL)                                              \
  do {                                                          \
    _Pragma("unroll") for (int i = 0; i < 2; i++) {             \
      gl_lds16(gsrcB[i], SMEM + (SL)*BSZ + ldofsB[i]);          \
      gsrcB[i] += 64;                                           \
    }                                                           \
  } while (0)

#define F8_CMP(SL)                                                             \
  do {                                                                         \
    const u8* Bs = SMEM + (SL)*BSZ;                                            \
    i32x8 bfv[2];                                                              \
    _Pragma("unroll") for (int ni = 0; ni < 2; ni++) {                         \
      const int r = wn * 64 + ni * 32 + c31;                                   \
      const int g = (r >> 1) & 3;                                              \
      const uint4 lo = *(const uint4*)(Bs + r * 64 + ((2 * hf) ^ g) * 16);     \
      const uint4 hi = *(const uint4*)(Bs + r * 64 + ((2 * hf + 1) ^ g) * 16); \
      bfv[ni] = i32x8{(int)lo.x, (int)lo.y, (int)lo.z, (int)lo.w,              \
                      (int)hi.x, (int)hi.y, (int)hi.z, (int)hi.w};             \
    }                                                                          \
    _Pragma("unroll") for (int mi = 0; mi < 2; mi++)                           \
      _Pragma("unroll") for (int ni = 0; ni < 2; ni++)                         \
        acc[mi][ni] = __builtin_amdgcn_mfma_scale_f32_32x32x64_f8f6f4(         \
            afr[SL][mi], bfv[ni], acc[mi][ni], 0, 0,                           \
            0, 0x7F7F7F7F,  /* A scale 2^0 */                                  \
            0, 0x79797979); /* B scale 2^-6 (weights pre-scaled x64) */        \
  } while (0)

  // prologue: tiles 0,1
  F8_LDA(0); F8_STB(0);
  F8_LDA(1); F8_STB(1);
  // NT = K/64 = 16 tiles; body t issues tile t+2 (slot (t+2)%3), computes t.
  for (int rep = 0; rep < 4; rep++) {   // t = 3*rep .. 3*rep+2 (t0..t11)
    WAITB(6); F8_LDA(2); F8_STB(2); F8_CMP(0);
    WAITB(6); F8_LDA(0); F8_STB(0); F8_CMP(1);
    WAITB(6); F8_LDA(1); F8_STB(1); F8_CMP(2);
  }
  WAITB(6); F8_LDA(2); F8_STB(2); F8_CMP(0);   // t12, issue t14
  WAITB(6); F8_LDA(0); F8_STB(0); F8_CMP(1);   // t13, issue t15
  WAITB(6); F8_CMP(2);                         // t14
  WAITB(0); F8_CMP(0);                         // t15
#undef F8_LDA
#undef F8_STB
#undef F8_CMP

  // C/D: col = lane&31, row = (reg&3) + 8*(reg>>2) + 4*(lane>>5)
#pragma unroll
  for (int mi = 0; mi < 2; mi++) {
    const int colo = (bx * 2 + wn) * 32 + c31;
#pragma unroll
    for (int reg = 0; reg < 16; reg++) {
      const int row = m0 + wm * 64 + mi * 32 + (reg & 3) + 8 * (reg >> 2) + 4 * hf;
      const float g = acc[mi][0][reg];
      const float u = acc[mi][1][reg];
      hid[(size_t)row * 4096 + colo] = f2bf(g / (1.f + __expf(-g)) * u);
    }
  }
}

// ---------------------------------------------------------------------------
// Causal attention (strict k<q), softmax = exp(s)/(sum+1e-9), flash-style.
// NEW: paired q-tiles for uniform work — grid (32 bh, 8 slots); each block
// runs qt = 15-slot (big) then qt = slot (small): 36 kt-tiles per block
// uniformly (was 20..48 per CU).  256 blocks.
// ---------------------------------------------------------------------------
__global__ __launch_bounds__(256) void attn_kernel(const u16* __restrict__ qkv,
                                                   const u16* __restrict__ vT,
                                                   u16* __restrict__ av) {
  __shared__ u16 SM[2 * 8192];
  __shared__ u16 Ps[4 * 2048];
  const int t = threadIdx.x, w = t >> 6, l = t & 63;
  const int lrow = l & 15, lk = l >> 4;
  const int bh = blockIdx.x;
  const int b = bh >> 4, h = bh & 15;
  u16* Pw = Ps + w * 2048;
  const float SC = 0.125f * 1.44269504088896f;  // log2(e)/8

  for (int pass = 0; pass < 2; pass++) {
    const int qt = pass == 0 ? (15 - (int)blockIdx.y) : (int)blockIdx.y;
    const int qbase = qt * 128 + w * 32;
    const int ktmax = 2 * qt + 1;

    __syncthreads();  // protect SM reuse across passes

    bf16x8 aq[2][2];
#pragma unroll
    for (int sub = 0; sub < 2; sub++)
#pragma unroll
      for (int half = 0; half < 2; half++)
        aq[sub][half] = *(const bf16x8*)(qkv + (size_t)(b * S_ + qbase + sub * 16 + lrow) * 3072 +
                                         h * 64 + half * 32 + lk * 8);

    const u16* gcur[4];
    int gstep[4], loff[4];
#pragma unroll
    for (int i = 0; i < 4; i++) {
      const int c = w + 4 * i;
      const int half = (c >> 2) & 1, grp = c & 3;
      if (c < 8) {
        gcur[i] = qkv + (size_t)(b * S_ + grp * 16 + (l >> 2)) * 3072 + D_ + h * 64 +
                  half * 32 + (l & 3) * 8;
        gstep[i] = 64 * 3072;
        loff[i] = half * 2048 + grp * 512;
      } else {
        gcur[i] = vT + (size_t)(bh * 64 + grp * 16 + (l >> 2)) * S_ + half * 32 + (l & 3) * 8;
        gstep[i] = 64;
        loff[i] = 4096 + half * 2048 + grp * 512;
      }
    }

    floatx4 oacc[2][4] = {};
    float den[2] = {0.f, 0.f};

    int cur = 0;
#pragma unroll
    for (int i = 0; i < 4; i++) { gl_lds16(gcur[i], SM + loff[i]); gcur[i] += gstep[i]; }

    for (int kt = 0; kt <= ktmax; kt++) {
      __syncthreads();
      if (kt < ktmax) {
#pragma unroll
        for (int i = 0; i < 4; i++) {
          gl_lds16(gcur[i], SM + (cur ^ 1) * 8192 + loff[i]);
          gcur[i] += gstep[i];
        }
      }
      const u16* Kbuf = SM + cur * 8192;
      const u16* Vbuf = Kbuf + 4096;

      // wave-uniform tile classification vs this wave's q rows [qbase, qbase+32)
      const bool active = (kt * 64 < qbase + 31);    // some k < some q
      if (active) {
        const bool need_mask = (kt * 64 + 64 > qbase);  // tile straddles diagonal

        bf16x8 bk[4][2];
#pragma unroll
        for (int ct = 0; ct < 4; ct++)
#pragma unroll
          for (int half = 0; half < 2; half++)
            bk[ct][half] = *(const bf16x8*)(Kbuf + half * 2048 + (ct * 16 + lrow) * 32 + lk * 8);

        floatx4 sf[2][4] = {};
        __builtin_amdgcn_s_setprio(1);
#pragma unroll
        for (int sub = 0; sub < 2; sub++)
#pragma unroll
          for (int ct = 0; ct < 4; ct++) {
            sf[sub][ct] = __builtin_amdgcn_mfma_f32_16x16x32_bf16(bk[ct][0], aq[sub][0],
                                                                  sf[sub][ct], 0, 0, 0);
            sf[sub][ct] = __builtin_amdgcn_mfma_f32_16x16x32_bf16(bk[ct][1], aq[sub][1],
                                                                  sf[sub][ct], 0, 0, 0);
          }
        __builtin_amdgcn_s_setprio(0);

        if (!need_mask) {
          // fast path: every k in tile < every q of this wave
#pragma unroll
          for (int sub = 0; sub < 2; sub++) {
            const int prow = sub * 16 + lrow;
#pragma unroll
            for (int ct = 0; ct < 4; ct++) {
              const float p0 = fexp2(sf[sub][ct][0] * SC);
              const float p1 = fexp2(sf[sub][ct][1] * SC);
              const float p2 = fexp2(sf[sub][ct][2] * SC);
              const float p3 = fexp2(sf[sub][ct][3] * SC);
              den[sub] += (p0 + p1) + (p2 + p3);
              uint2 pk;
              pk.x = cvtpk_bf16(p0, p1);
              pk.y = cvtpk_bf16(p2, p3);
              *(uint2*)(Pw + prow * 64 + (((2 * ct + (lk >> 1)) ^ (lrow & 7)) << 3) +
                        (lk & 1) * 4) = pk;
            }
          }
        } else {
#pragma unroll
          for (int sub = 0; sub < 2; sub++) {
            const int qp = qbase + sub * 16 + lrow;
            const int prow = sub * 16 + lrow;
#pragma unroll
            for (int ct = 0; ct < 4; ct++) {
              const int kb = kt * 64 + ct * 16 + lk * 4;
              const float p0 = (kb + 0 < qp) ? fexp2(sf[sub][ct][0] * SC) : 0.f;
              const float p1 = (kb + 1 < qp) ? fexp2(sf[sub][ct][1] * SC) : 0.f;
              const float p2 = (kb + 2 < qp) ? fexp2(sf[sub][ct][2] * SC) : 0.f;
              const float p3 = (kb + 3 < qp) ? fexp2(sf[sub][ct][3] * SC) : 0.f;
              den[sub] += (p0 + p1) + (p2 + p3);
              uint2 pk;
              pk.x = cvtpk_bf16(p0, p1);
              pk.y = cvtpk_bf16(p2, p3);
              *(uint2*)(Pw + prow * 64 + (((2 * ct + (lk >> 1)) ^ (lrow & 7)) << 3) +
                        (lk & 1) * 4) = pk;
            }
          }
        }

        bf16x8 ap[2][2], bv[4][2];
#pragma unroll
        for (int sub = 0; sub < 2; sub++)
#pragma unroll
          for (int kh = 0; kh < 2; kh++) {
            const int prow = sub * 16 + lrow;
            ap[sub][kh] = *(const bf16x8*)(Pw + prow * 64 + (((kh * 4 + lk) ^ (prow & 7)) << 3));
          }
#pragma unroll
        for (int ni = 0; ni < 4; ni++)
#pragma unroll
          for (int kh = 0; kh < 2; kh++)
            bv[ni][kh] = *(const bf16x8*)(Vbuf + kh * 2048 + (ni * 16 + lrow) * 32 + lk * 8);
        __builtin_amdgcn_s_setprio(1);
#pragma unroll
        for (int sub = 0; sub < 2; sub++)
#pragma unroll
          for (int ni = 0; ni < 4; ni++) {
            oacc[sub][ni] = __builtin_amdgcn_mfma_f32_16x16x32_bf16(ap[sub][0], bv[ni][0],
                                                                    oacc[sub][ni], 0, 0, 0);
            oacc[sub][ni] = __builtin_amdgcn_mfma_f32_16x16x32_bf16(ap[sub][1], bv[ni][1],
                                                                    oacc[sub][ni], 0, 0, 0);
          }
        __builtin_amdgcn_s_setprio(0);
      }
      cur ^= 1;
    }

#pragma unroll
    for (int sub = 0; sub < 2; sub++) {
      den[sub] += __shfl_xor(den[sub], 16);
      den[sub] += __shfl_xor(den[sub], 32);
    }
    float dq[2][4];
#pragma unroll
    for (int sub = 0; sub < 2; sub++)
#pragma unroll
      for (int r = 0; r < 4; r++)
        dq[sub][r] = __shfl(den[sub], lk * 4 + r);

#pragma unroll
    for (int sub = 0; sub < 2; sub++)
#pragma unroll
      for (int ni = 0; ni < 4; ni++)
#pragma unroll
        for (int r = 0; r < 4; r++) {
          const int row = qbase + sub * 16 + lk * 4 + r;
          const int col = h * 64 + ni * 16 + lrow;
          av[(size_t)(b * S_ + row) * 1024 + col] = f2bf(oacc[sub][ni][r] / (dq[sub][r] + 1e-9f));
        }
  }
}

// ---------------------------------------------------------------------------
// Workspace layout (bytes)
// ---------------------------------------------------------------------------
#define OFF_WQKV 0u            // [3072][1024] bf16
#define OFF_WO   6291456u      // [1024][1024] bf16
#define OFF_WGU8 8388608u      // [8192][1024] fp8 (gate/up 32-col interleaved, x64)
#define OFF_WDN  16777216u     // [1024][4096] bf16
#define OFF_H1   25165824u     // [4096][1024] bf16
#define OFF_QKV  33554432u     // [4096][3072] bf16 (V region unused)
#define OFF_VT   58720256u     // [2][16][64][2048] bf16
#define OFF_AV   67108864u     // [4096][1024] bf16
#define OFF_X1   75497472u     // [4096][1024] f32
#define OFF_H2F8 92274688u     // [4096][1024] fp8 (fragment-major A')
#define OFF_HID  96468992u     // [4096][4096] bf16

extern "C" void kernel_launch(void* const* d_in, const int* in_sizes, int n_in,
                              void* d_out, int out_size, void* d_ws, size_t ws_size,
                              hipStream_t stream) {
  const float* x      = (const float*)d_in[0];
  const float* w_q    = (const float*)d_in[1];
  const float* w_k    = (const float*)d_in[2];
  const float* w_v    = (const float*)d_in[3];
  const float* w_o    = (const float*)d_in[4];
  const float* w_gate = (const float*)d_in[5];
  const float* w_up   = (const float*)d_in[6];
  const float* w_down = (const float*)d_in[7];
  const float* g1     = (const float*)d_in[8];
  const float* g2     = (const float*)d_in[9];

  char* ws = (char*)d_ws;
  u16* wqkv_t = (u16*)(ws + OFF_WQKV);
  u16* wo_t   = (u16*)(ws + OFF_WO);
  u8*  wguf8  = (u8*)(ws + OFF_WGU8);
  u16* wdn_t  = (u16*)(ws + OFF_WDN);
  u16* h1     = (u16*)(ws + OFF_H1);
  u16* qkv    = (u16*)(ws + OFF_QKV);
  u16* vT     = (u16*)(ws + OFF_VT);
  u16* av     = (u16*)(ws + OFF_AV);
  float* x1   = (float*)(ws + OFF_X1);
  u8*  h2f8   = (u8*)(ws + OFF_H2F8);
  u16* hid    = (u16*)(ws + OFF_HID);
  float* out  = (float*)d_out;

  prep_weights<<<16384, dim3(32, 8), 0, stream>>>(w_q, w_k, w_v, w_o, w_gate, w_up, w_down,
                                                  wqkv_t, wo_t, wguf8, wdn_t);

  rmsnorm_kernel<0><<<BS_, 256, 0, stream>>>(x, g1, h1);
  // qkv GEMM: BN=128 (wave tile 64x64), 2-buf counted pipe; V blocks -> vT
  gemm_bt<128, 3><<<dim3(3072 / 128, BS_ / 128), 256, 0, stream>>>(
      h1, wqkv_t, qkv, nullptr, vT, BS_, 3072, 1024);
  // attn: paired q-tiles, uniform 36 kt-tiles/block, 256 blocks
  attn_kernel<<<dim3(32, 8), 256, 0, stream>>>(qkv, vT, av);
  gemm_bt<64, 1><<<dim3(1024 / 64, BS_ / 128), 256, 0, stream>>>(
      av, wo_t, x1, x, nullptr, BS_, 1024, 1024);
  rmsnorm_kernel<1><<<BS_, 256, 0, stream>>>(x1, g2, h2f8);
  // fused gate/up GEMM in MX-fp8: A direct-from-global (fragment-major),
  // B-only LDS ring, L2-tiled XCD traversal
  gemm_f8<<<dim3(64, 32), 256, 0, stream>>>(h2f8, wguf8, hid, BS_, 1024);
  gemm_bt<64, 1><<<dim3(1024 / 64, BS_ / 128), 256, 0, stream>>>(
      hid, wdn_t, out, x1, nullptr, BS_, 1024, 4096);
}